// Round 8
// baseline (560.528 us; speedup 1.0000x reference)
//
#include <hip/hip_runtime.h>
#include <hip/hip_bf16.h>

#define NSP 4096   // H*W
#define CCH 256    // C
#define CIN 128    // Ci
#define BN_EPS 1e-5f

typedef __bf16 bf16x8 __attribute__((ext_vector_type(8)));
typedef __bf16 bf16x4 __attribute__((ext_vector_type(4)));
typedef float f32x4 __attribute__((ext_vector_type(4)));

// ================= fp32 tile helpers (prep only) =================================

__device__ __forceinline__ float4 fetch_tr(const float* __restrict__ A, int lda, int m0,
                                           int k0, int tid) {
  const int r = tid >> 2, kq = (tid & 3) << 2;
  return *(const float4*)(A + (size_t)(m0 + r) * lda + k0 + kq);
}
__device__ __forceinline__ void stash_tr(float (*As)[68], float4 v, int tid) {
  const int r = tid >> 2, kq = (tid & 3) << 2;
  As[kq + 0][r] = v.x; As[kq + 1][r] = v.y; As[kq + 2][r] = v.z; As[kq + 3][r] = v.w;
}
__device__ __forceinline__ float4 fetch_dir(const float* __restrict__ B, int ldb, int k0,
                                            int n0, int tid) {
  const int kr = tid >> 4, nq = (tid & 15) << 2;
  return *(const float4*)(B + (size_t)(k0 + kr) * ldb + n0 + nq);
}
__device__ __forceinline__ void stash_dir(float (*Bs)[68], float4 v, int tid) {
  const int kr = tid >> 4, nq = (tid & 15) << 2;
  *(float4*)(&Bs[kr][nq]) = v;
}

__device__ __forceinline__ void mm16(const float (*As)[68], const float (*Bs)[68],
                                     float acc[4][4], int ty, int tx) {
#pragma unroll
  for (int kk = 0; kk < 16; ++kk) {
    const float4 av = *(const float4*)(&As[kk][ty << 2]);
    const float4 bv = *(const float4*)(&Bs[kk][tx << 2]);
    const float ar[4] = {av.x, av.y, av.z, av.w};
    const float br[4] = {bv.x, bv.y, bv.z, bv.w};
#pragma unroll
    for (int i = 0; i < 4; ++i)
#pragma unroll
      for (int j = 0; j < 4; ++j) acc[i][j] += ar[i] * br[j];
  }
}

__device__ __forceinline__ float wave_reduce(float v) {
#pragma unroll
  for (int off = 32; off; off >>= 1) v += __shfl_down(v, off);
  return v;  // valid in lane 0
}

// device-scope multi-phase barrier: cumulative counter, targets 512/1024/1536/2048
__device__ __forceinline__ void gbarrier(int* cnt, int target, int tid) {
  __syncthreads();
  if (tid == 0) {
    __threadfence();  // release: flush XCD L2 so other XCDs see our writes
    __hip_atomic_fetch_add(cnt, 1, __ATOMIC_ACQ_REL, __HIP_MEMORY_SCOPE_AGENT);
    while (__hip_atomic_load(cnt, __ATOMIC_ACQUIRE, __HIP_MEMORY_SCOPE_AGENT) < target)
      __builtin_amdgcn_s_sleep(2);
  }
  __syncthreads();
  __threadfence();    // acquire: invalidate stale L1/L2 before reading remote data
}

// ===== setup grid 2087: cast_b(0..1023) + prep(1024..1055) + cast_a(1056..2079)
// ===== + vb/d1(2080) + vpt(2081) + wgb(2082..2085) + cnt-init(2086)
__global__ __launch_bounds__(256) void setup_kernel(
    const float* __restrict__ bin, __bf16* __restrict__ bhi, __bf16* __restrict__ blo,
    float* __restrict__ srow, const float* __restrict__ W_w, const float* __restrict__ g_w,
    const float* __restrict__ phi_w, const float* __restrict__ theta_w,
    float* __restrict__ Wg, __bf16* __restrict__ Wghi, __bf16* __restrict__ Wglo,
    __bf16* __restrict__ PTthi, __bf16* __restrict__ PTtlo,
    const float* __restrict__ a, __bf16* __restrict__ at,
    const float* __restrict__ phi_b, const float* __restrict__ theta_b,
    const float* __restrict__ g_b,
    float* __restrict__ vb_g, float* __restrict__ vpt, float* __restrict__ wgb,
    float* __restrict__ dvec, int* __restrict__ cnt) {
  __shared__ float smem[64 * 68];
  const int idx = blockIdx.x;
  const int t = threadIdx.x;
  const int wave = t >> 6, lane = t & 63;
  if (idx < 1024) {
    // ---- cast b row -> bf16 hi/lo + exact fp32 row sum ----
    const int row = idx;
    const float* src = bin + (size_t)row * NSP + t * 16;
    float sum = 0.f;
    __bf16 hi[16], lo[16];
#pragma unroll
    for (int i = 0; i < 4; ++i) {
      const float4 v = *(const float4*)(src + i * 4);
      const float vv[4] = {v.x, v.y, v.z, v.w};
#pragma unroll
      for (int j = 0; j < 4; ++j) {
        const float x = vv[j];
        sum += x;
        const __bf16 h = (__bf16)x;
        hi[i * 4 + j] = h;
        lo[i * 4 + j] = (__bf16)(x - (float)h);
      }
    }
    __bf16* dh = bhi + (size_t)row * NSP + t * 16;
    __bf16* dl = blo + (size_t)row * NSP + t * 16;
    *(bf16x8*)dh = *(bf16x8*)&hi[0];
    *(bf16x8*)(dh + 8) = *(bf16x8*)&hi[8];
    *(bf16x8*)dl = *(bf16x8*)&lo[0];
    *(bf16x8*)(dl + 8) = *(bf16x8*)&lo[8];
#pragma unroll
    for (int off = 32; off; off >>= 1) sum += __shfl_down(sum, off);
    if ((t & 63) == 0) smem[t >> 6] = sum;
    __syncthreads();
    if (t == 0) srow[row] = smem[0] + smem[1] + smem[2] + smem[3];
  } else if (idx < 1056) {
    // ---- prep: Wg = W_w @ g_w (z=0, fp32+hi/lo) ; PTt = theta_w^T @ phi_w (z=1)
    const int p = idx - 1024;
    const int zsel = p >> 4, rem = p & 15;
    const int m0 = (rem >> 2) * 64, n0 = (rem & 3) * 64;
    float (*As)[68] = (float(*)[68])smem;
    float (*Bs)[68] = (float(*)[68])(smem + 16 * 68);
    const int ty = t >> 4, tx = t & 15;
    float acc[4][4] = {};
    if (zsel == 0) {
      float4 ar = fetch_tr(W_w, CIN, m0, 0, t);
      float4 br = fetch_dir(g_w, CCH, 0, n0, t);
      for (int kt = 0; kt < 8; ++kt) {
        stash_tr(As, ar, t); stash_dir(Bs, br, t);
        __syncthreads();
        if (kt < 7) { ar = fetch_tr(W_w, CIN, m0, (kt + 1) * 16, t);
                      br = fetch_dir(g_w, CCH, (kt + 1) * 16, n0, t); }
        mm16(As, Bs, acc, ty, tx);
        __syncthreads();
      }
#pragma unroll
      for (int i = 0; i < 4; ++i) {
        const size_t off = (size_t)(m0 + (ty << 2) + i) * 256 + n0 + (tx << 2);
        *(float4*)(Wg + off) = make_float4(acc[i][0], acc[i][1], acc[i][2], acc[i][3]);
        __bf16 h4[4], l4[4];
#pragma unroll
        for (int j = 0; j < 4; ++j) {
          const __bf16 h = (__bf16)acc[i][j];
          h4[j] = h; l4[j] = (__bf16)(acc[i][j] - (float)h);
        }
        *(bf16x4*)(Wghi + off) = *(bf16x4*)h4;
        *(bf16x4*)(Wglo + off) = *(bf16x4*)l4;
      }
    } else {
      float4 ar = fetch_dir(theta_w, CCH, 0, m0, t);   // swapped: computes PT^T
      float4 br = fetch_dir(phi_w, CCH, 0, n0, t);
      for (int kt = 0; kt < 8; ++kt) {
        stash_dir(As, ar, t); stash_dir(Bs, br, t);
        __syncthreads();
        if (kt < 7) { ar = fetch_dir(theta_w, CCH, (kt + 1) * 16, m0, t);
                      br = fetch_dir(phi_w, CCH, (kt + 1) * 16, n0, t); }
        mm16(As, Bs, acc, ty, tx);
        __syncthreads();
      }
#pragma unroll
      for (int i = 0; i < 4; ++i) {
        const size_t off = (size_t)(m0 + (ty << 2) + i) * 256 + n0 + (tx << 2);
        __bf16 h4[4], l4[4];
#pragma unroll
        for (int j = 0; j < 4; ++j) {
          const __bf16 h = (__bf16)acc[i][j];
          h4[j] = h; l4[j] = (__bf16)(acc[i][j] - (float)h);
        }
        *(bf16x4*)(PTthi + off) = *(bf16x4*)h4;
        *(bf16x4*)(PTtlo + off) = *(bf16x4*)l4;
      }
    }
  } else if (idx < 2080) {
    // ---- cast a -> bf16 transposed: at[b][n][c] ----
    const int p = idx - 1056;
    const int n0 = (p & 63) * 64, c0 = ((p >> 6) & 3) * 64, b = p >> 8;
    float (*tile)[68] = (float(*)[68])smem;
    const int cr = t >> 4, nq = (t & 15) << 2;
    const float* src = a + ((size_t)(b * CCH + c0)) * NSP + n0;
#pragma unroll
    for (int s = 0; s < 4; ++s) {
      const float4 v = *(const float4*)(src + (size_t)(cr + s * 16) * NSP + nq);
      *(float4*)&tile[cr + s * 16][nq] = v;
    }
    __syncthreads();
    const int n = t >> 2, cq = (t & 3) << 4;
    __bf16 outv[16];
#pragma unroll
    for (int i = 0; i < 16; ++i) outv[i] = (__bf16)tile[cq + i][n];
    __bf16* dst = at + ((size_t)(b * NSP + n0 + n)) * CCH + c0 + cq;
    *(bf16x8*)dst = *(bf16x8*)&outv[0];
    *(bf16x8*)(dst + 8) = *(bf16x8*)&outv[8];
  } else if (idx == 2080) {
    // ---- vb[c] = phi_w^T @ theta_b ; d1 = phi_b . theta_b ----
    float* tb_s = smem;
    float* pb_s = smem + 128;
    if (t < 128) { tb_s[t] = theta_b[t]; pb_s[t] = phi_b[t]; }
    __syncthreads();
    float acc = 0.f;
#pragma unroll 8
    for (int i = 0; i < 128; ++i) acc += phi_w[(size_t)i * 256 + t] * tb_s[i];
    vb_g[t] = acc;
    if (t < 64) {
      float pv = pb_s[t] * tb_s[t] + pb_s[t + 64] * tb_s[t + 64];
      pv = wave_reduce(pv);
      if (t == 0) dvec[0] = pv;
    }
  } else if (idx == 2081) {
    // ---- vpt[c] = phi_b^T @ theta_w (coalesced cols) ----
    float* pb_s = smem;
    if (t < 128) pb_s[t] = phi_b[t];
    __syncthreads();
    float acc = 0.f;
#pragma unroll 8
    for (int i = 0; i < 128; ++i) acc += pb_s[i] * theta_w[(size_t)i * 256 + t];
    vpt[t] = acc;
  } else if (idx < 2086) {
    // ---- wgb[o] = W_w[o] . g_b : 4 blocks x 64 outputs ----
    const int p = idx - 2082;
    float* gb_s = smem;
    if (t < 128) gb_s[t] = g_b[t];
    __syncthreads();
    const float2 gv = *(const float2*)&gb_s[lane * 2];
    for (int i = 0; i < 16; ++i) {
      const int o = p * 64 + wave * 16 + i;
      const float2 r = *(const float2*)(W_w + (size_t)o * 128 + lane * 2);
      float v = fmaf(r.x, gv.x, r.y * gv.y);
      v = wave_reduce(v);
      if (lane == 0) wgb[o] = v;
    }
  } else {
    if (t == 0) *cnt = 0;   // barrier counter init (ws is poisoned 0xAA each call)
  }
}

// ================= mega: gram -> reduce+aux -> w2 -> wout+bias -> out ============
// 512 blocks x 256 thr, __launch_bounds__(256,4): VGPR<=128 -> >=4 blocks/CU
// capacity (1024 slots >= 512 blocks) -> all blocks co-resident, barriers safe.
__global__ __launch_bounds__(256, 4) void mega_kernel(
    const __bf16* __restrict__ bhi, const __bf16* __restrict__ blo,
    float* __restrict__ Gpart,
    __bf16* __restrict__ Ghi, __bf16* __restrict__ Glo,
    const float* __restrict__ vb_g, float* __restrict__ t2_g,
    const float* __restrict__ srow, const float* __restrict__ Wg,
    const __bf16* __restrict__ Wghi, const __bf16* __restrict__ Wglo,
    const __bf16* __restrict__ PTthi, const __bf16* __restrict__ PTtlo,
    __bf16* __restrict__ W2hi, __bf16* __restrict__ W2lo,
    float* __restrict__ Wgs, float* __restrict__ sPTv,
    const float* __restrict__ wgb, const float* __restrict__ vpt,
    float* __restrict__ dvec,
    const float* __restrict__ bn_gamma, const float* __restrict__ bn_beta,
    const float* __restrict__ bn_mean, const float* __restrict__ bn_var,
    __bf16* __restrict__ Whi, __bf16* __restrict__ Wlo,
    float* __restrict__ bias_out,
    const __bf16* __restrict__ at, float* __restrict__ out,
    int* __restrict__ cnt) {
  const int blk = blockIdx.x;
  const int t = threadIdx.x;
  const int wave = t >> 6, lane = t & 63;
  const int m = lane & 15, q = lane >> 4;
  __shared__ float lds[256];

  // ---- P0: gram partials (1024 units, 2 per block) ----
  for (int u = blk; u < 1024; u += 512) {
    const int jt = u & 3, it = (u >> 2) & 3;
    const int z = u >> 4, batch = z >> 4, kc = z & 15;
    const size_t base = (size_t)batch * CCH * NSP;
    const size_t arow = base + (size_t)(it * 64 + wave * 16 + m) * NSP + kc * 256 + q * 8;
    const size_t brow = base + (size_t)(jt * 64 + m) * NSP + kc * 256 + q * 8;
    f32x4 acc[4] = {};
#pragma unroll
    for (int ks = 0; ks < 8; ++ks) {
      const int k = ks * 32;
      const bf16x8 ah = *(const bf16x8*)(bhi + arow + k);
      const bf16x8 al = *(const bf16x8*)(blo + arow + k);
#pragma unroll
      for (int t4 = 0; t4 < 4; ++t4) {
        const size_t boff = brow + (size_t)t4 * 16 * NSP + k;
        const bf16x8 bh = *(const bf16x8*)(bhi + boff);
        const bf16x8 bl = *(const bf16x8*)(blo + boff);
        acc[t4] = __builtin_amdgcn_mfma_f32_16x16x32_bf16(ah, bh, acc[t4], 0, 0, 0);
        acc[t4] = __builtin_amdgcn_mfma_f32_16x16x32_bf16(ah, bl, acc[t4], 0, 0, 0);
        acc[t4] = __builtin_amdgcn_mfma_f32_16x16x32_bf16(al, bh, acc[t4], 0, 0, 0);
      }
    }
    float* Gp = Gpart + ((size_t)(kc * 4 + batch)) * 65536;
#pragma unroll
    for (int t4 = 0; t4 < 4; ++t4)
#pragma unroll
      for (int r = 0; r < 4; ++r)
        Gp[(size_t)(it * 64 + wave * 16 + q * 4 + r) * 256 + jt * 64 + t4 * 16 + m] =
            acc[t4][r];
  }
  gbarrier(cnt, 512, t);

  // ---- P1: reduce -> Ghi/Glo + t2 (blk<256) ; aux Wgs/sPTv/d2 (256..319) ----
  if (blk < 256) {
    lds[t] = vb_g[t];
    __syncthreads();
    const int v4 = blk * 256 + t;          // float4 index into G (65536 total)
    const int batch = v4 >> 14;
    f32x4 s = {};
#pragma unroll
    for (int p = 0; p < 16; ++p)
      s += *(const f32x4*)(Gpart + (((size_t)(p * 4 + batch)) << 16) +
                           ((size_t)(v4 & 16383) << 2));
    __bf16 h4[4], l4[4];
#pragma unroll
    for (int e = 0; e < 4; ++e) {
      const __bf16 h = (__bf16)s[e];
      h4[e] = h; l4[e] = (__bf16)(s[e] - (float)h);
    }
    *(bf16x4*)(Ghi + ((size_t)v4 << 2)) = *(bf16x4*)h4;
    *(bf16x4*)(Glo + ((size_t)v4 << 2)) = *(bf16x4*)l4;
    // t2[row] = G[row].vb ; row = v4>>6 (one row per wave)
    const float vb0 = lds[lane * 4], vb1 = lds[lane * 4 + 1];
    const float vb2 = lds[lane * 4 + 2], vb3 = lds[lane * 4 + 3];
    float d = fmaf(s[0], vb0, fmaf(s[1], vb1, fmaf(s[2], vb2, s[3] * vb3)));
    d = wave_reduce(d);
    if (lane == 0) t2_g[v4 >> 6] = d;
  } else if (blk < 320) {
    const int b = (blk - 256) >> 4, seg = (blk - 256) & 15;
    lds[t] = srow[b * 256 + t];
    __syncthreads();
    const float4 sv = *(const float4*)&lds[lane * 4];
    for (int i = wave; i < 16; i += 4) {  // Wgs[o] = Wg[o].s
      const int o = seg * 16 + i;
      const float4 r = *(const float4*)(Wg + (size_t)o * 256 + lane * 4);
      float v = fmaf(r.x, sv.x, fmaf(r.y, sv.y, fmaf(r.z, sv.z, r.w * sv.w)));
      v = wave_reduce(v);
      if (lane == 0) Wgs[b * 256 + o] = v;
    }
    for (int i = wave; i < 16; i += 4) {  // sPTv[c] = PTt[c].s (hi+lo reconstruct)
      const int c = seg * 16 + i;
      const bf16x4 ph = *(const bf16x4*)(PTthi + (size_t)c * 256 + lane * 4);
      const bf16x4 pl = *(const bf16x4*)(PTtlo + (size_t)c * 256 + lane * 4);
      const float svv[4] = {sv.x, sv.y, sv.z, sv.w};
      float v = 0.f;
#pragma unroll
      for (int e = 0; e < 4; ++e) v += ((float)ph[e] + (float)pl[e]) * svv[e];
      v = wave_reduce(v);
      if (lane == 0) sPTv[b * 256 + c] = v;
    }
    if (seg == 0 && wave == 0) {          // d2 = s . vb
      const float4 vbv = *(const float4*)(vb_g + lane * 4);
      float v = fmaf(vbv.x, sv.x, fmaf(vbv.y, sv.y, fmaf(vbv.z, sv.z, vbv.w * sv.w)));
      v = wave_reduce(v);
      if (lane == 0) dvec[1 + b] = v;
    }
  }
  gbarrier(cnt, 1024, t);

  // ---- P2: W2 = Wg @ G[b] (1024 tiles, 1/wave; G symmetric -> B-frag = rows) ----
  if (blk < 256) {
    const int tile = blk * 4 + wave;
    const int batch = tile >> 8, rem = tile & 255;
    const int mt = rem >> 4, nt = rem & 15;
    const __bf16* ah_p = Wghi + (size_t)(mt * 16 + m) * 256;
    const __bf16* al_p = Wglo + (size_t)(mt * 16 + m) * 256;
    const __bf16* bh_p = Ghi + (size_t)batch * 65536 + (size_t)(nt * 16 + m) * 256;
    const __bf16* bl_p = Glo + (size_t)batch * 65536 + (size_t)(nt * 16 + m) * 256;
    f32x4 acc = {};
#pragma unroll
    for (int ks = 0; ks < 8; ++ks) {
      const int k = ks * 32 + q * 8;
      const bf16x8 ah = *(const bf16x8*)(ah_p + k);
      const bf16x8 al = *(const bf16x8*)(al_p + k);
      const bf16x8 bh = *(const bf16x8*)(bh_p + k);
      const bf16x8 bl = *(const bf16x8*)(bl_p + k);
      acc = __builtin_amdgcn_mfma_f32_16x16x32_bf16(ah, bh, acc, 0, 0, 0);
      acc = __builtin_amdgcn_mfma_f32_16x16x32_bf16(ah, bl, acc, 0, 0, 0);
      acc = __builtin_amdgcn_mfma_f32_16x16x32_bf16(al, bh, acc, 0, 0, 0);
    }
#pragma unroll
    for (int r = 0; r < 4; ++r) {
      const size_t off = (size_t)batch * 65536 + (size_t)(mt * 16 + q * 4 + r) * 256 +
                         nt * 16 + m;
      const float v = acc[r];
      const __bf16 h = (__bf16)v;
      W2hi[off] = h;
      W2lo[off] = (__bf16)(v - (float)h);
    }
  }
  gbarrier(cnt, 1536, t);

  // ---- P3: W_out tiles (blk<256) + bias chain (256..287) ----
  if (blk < 256) {
    const int tile = blk * 4 + wave;
    const int batch = tile >> 8, rem = tile & 255;
    const int mt = rem >> 4, nt = rem & 15;
    const __bf16* ah_p = W2hi + (size_t)batch * 65536 + (size_t)(mt * 16 + m) * 256;
    const __bf16* al_p = W2lo + (size_t)batch * 65536 + (size_t)(mt * 16 + m) * 256;
    const __bf16* bh_p = PTthi + (size_t)(nt * 16 + m) * 256;  // PTt row = PT column
    const __bf16* bl_p = PTtlo + (size_t)(nt * 16 + m) * 256;
    f32x4 acc = {};
#pragma unroll
    for (int ks = 0; ks < 8; ++ks) {
      const int k = ks * 32 + q * 8;
      const bf16x8 ah = *(const bf16x8*)(ah_p + k);
      const bf16x8 al = *(const bf16x8*)(al_p + k);
      const bf16x8 bh = *(const bf16x8*)(bh_p + k);
      const bf16x8 bl = *(const bf16x8*)(bl_p + k);
      acc = __builtin_amdgcn_mfma_f32_16x16x32_bf16(ah, bh, acc, 0, 0, 0);
      acc = __builtin_amdgcn_mfma_f32_16x16x32_bf16(ah, bl, acc, 0, 0, 0);
      acc = __builtin_amdgcn_mfma_f32_16x16x32_bf16(al, bh, acc, 0, 0, 0);
    }
    const float invN = 1.0f / 4096.0f;
    const int c = nt * 16 + m;
    const float vpt_c = vpt[c];
    const float sPT_c = sPTv[batch * 256 + c];
#pragma unroll
    for (int r = 0; r < 4; ++r) {
      const int o = mt * 16 + q * 4 + r;
      const float sc = bn_gamma[o] * rsqrtf(bn_var[o] + BN_EPS);
      const float w = sc * ((acc[r] + Wgs[batch * 256 + o] * vpt_c + wgb[o] * sPT_c) * invN +
                            wgb[o] * vpt_c);
      const size_t off = (size_t)batch * 65536 + (size_t)o * 256 + c;
      const __bf16 h = (__bf16)w;
      Whi[off] = h;
      Wlo[off] = (__bf16)(w - (float)h);
    }
  } else if (blk < 288) {
    // bias = sc*((Wg@t2 + Wgs*d1 + wgb*(d2+N*d1))/N - mean) + beta
    const int p = blk - 256;
    const int b = p >> 3, oct = p & 7;
    lds[t] = t2_g[b * 256 + t];
    __syncthreads();
    const float d1 = dvec[0], d2 = dvec[1 + b];
    const float invN = 1.0f / 4096.0f;
    const float4 tv = *(const float4*)&lds[lane * 4];
    for (int i = 0; i < 8; ++i) {
      const int o = oct * 32 + wave * 8 + i;
      const float4 r = *(const float4*)(Wg + (size_t)o * 256 + lane * 4);
      float v = fmaf(r.x, tv.x, fmaf(r.y, tv.y, fmaf(r.z, tv.z, r.w * tv.w)));
      v = wave_reduce(v);
      if (lane == 0) {
        const float bias_full = (v + Wgs[b * 256 + o] * d1 +
                                 wgb[o] * (d2 + 4096.0f * d1)) * invN;
        const float sc = bn_gamma[o] * rsqrtf(bn_var[o] + BN_EPS);
        bias_out[b * 256 + o] = sc * (bias_full - bn_mean[o]) + bn_beta[o];
      }
    }
  }
  gbarrier(cnt, 2048, t);

  // ---- P4: out[b] = W_out[b] @ a[b] + bias (2048 units, 4 per block) ----
#pragma unroll
  for (int i = 0; i < 4; ++i) {
    const int unit = blk * 4 + i;
    const int nt = unit & 127, mt = (unit >> 7) & 3, b = unit >> 9;
    const int o = mt * 64 + wave * 16 + m;
    const __bf16* wh = Whi + (size_t)b * 65536 + (size_t)o * 256;
    const __bf16* wl = Wlo + (size_t)b * 65536 + (size_t)o * 256;
    const __bf16* atb = at + ((size_t)b * NSP + nt * 32) * CCH;
    f32x4 acc[2] = {};
#pragma unroll
    for (int ks = 0; ks < 8; ++ks) {
      const int k = ks * 32 + q * 8;
      const bf16x8 ah = *(const bf16x8*)(wh + k);
      const bf16x8 al = *(const bf16x8*)(wl + k);
#pragma unroll
      for (int t4 = 0; t4 < 2; ++t4) {
        const bf16x8 bh = *(const bf16x8*)(atb + (size_t)(t4 * 16 + m) * 256 + k);
        acc[t4] = __builtin_amdgcn_mfma_f32_16x16x32_bf16(ah, bh, acc[t4], 0, 0, 0);
        acc[t4] = __builtin_amdgcn_mfma_f32_16x16x32_bf16(al, bh, acc[t4], 0, 0, 0);
      }
    }
    float* ob = out + (size_t)b * CCH * NSP;
#pragma unroll
    for (int r = 0; r < 4; ++r) {
      const int orow = mt * 64 + wave * 16 + q * 4 + r;
      const float bo = bias_out[b * 256 + orow];
#pragma unroll
      for (int t4 = 0; t4 < 2; ++t4)
        ob[(size_t)orow * NSP + nt * 32 + t4 * 16 + m] = acc[t4][r] + bo;
    }
  }
}

extern "C" void kernel_launch(void* const* d_in, const int* in_sizes, int n_in,
                              void* d_out, int out_size, void* d_ws, size_t ws_size,
                              hipStream_t stream) {
  (void)in_sizes; (void)n_in; (void)out_size; (void)ws_size;
  const float* a       = (const float*)d_in[0];
  const float* bI      = (const float*)d_in[1];
  const float* theta_w = (const float*)d_in[2];
  const float* theta_b = (const float*)d_in[3];
  const float* phi_w   = (const float*)d_in[4];
  const float* phi_b   = (const float*)d_in[5];
  const float* g_w     = (const float*)d_in[6];
  const float* g_b     = (const float*)d_in[7];
  const float* W_w     = (const float*)d_in[8];
  const float* bn_gamma= (const float*)d_in[9];
  const float* bn_beta = (const float*)d_in[10];
  const float* bn_mean = (const float*)d_in[11];
  const float* bn_var  = (const float*)d_in[12];
  float* out = (float*)d_out;
  float* ws  = (float*)d_ws;

  // fp32 region (float offsets)
  float* Gpart    = ws;                  // 4194304 (16 MB)
  float* srow     = ws + 4194304;        // 1024
  float* Wg       = ws + 4195328;        // 65536
  float* bias_out = ws + 4260864;        // 1024
  float* Wgs      = ws + 4261888;        // 1024
  float* sPTv     = ws + 4262912;        // 1024
  float* wgb      = ws + 4263936;        // 256
  float* vpt      = ws + 4264192;        // 256
  float* vb_g     = ws + 4264448;        // 256
  float* t2_g     = ws + 4264704;        // 1024
  float* dvec     = ws + 4265728;        // 8
  int*   cnt      = (int*)(ws + 4265792);// 64 floats reserved
  // bf16 region
  __bf16* bhi   = (__bf16*)(ws + 4265984);   // 8 MB
  __bf16* blo   = (__bf16*)(ws + 6363136);   // 8 MB
  __bf16* at    = (__bf16*)(ws + 8460288);   // 8 MB
  __bf16* Wghi  = (__bf16*)(ws + 10557440);  // 128 KB each below
  __bf16* Wglo  = (__bf16*)(ws + 10590208);
  __bf16* PTthi = (__bf16*)(ws + 10622976);
  __bf16* PTtlo = (__bf16*)(ws + 10655744);
  __bf16* Ghi   = (__bf16*)(ws + 10688512);  // 512 KB each below
  __bf16* Glo   = (__bf16*)(ws + 10819584);
  __bf16* W2hi  = (__bf16*)(ws + 10950656);
  __bf16* W2lo  = (__bf16*)(ws + 11081728);
  __bf16* Whi   = (__bf16*)(ws + 11212800);
  __bf16* Wlo   = (__bf16*)(ws + 11343872); // end ~45.9 MB

  setup_kernel<<<dim3(2087), dim3(256), 0, stream>>>(bI, bhi, blo, srow, W_w, g_w, phi_w,
                                                     theta_w, Wg, Wghi, Wglo, PTthi, PTtlo,
                                                     a, at, phi_b, theta_b, g_b,
                                                     vb_g, vpt, wgb, dvec, cnt);
  mega_kernel<<<dim3(512), dim3(256), 0, stream>>>(bhi, blo, Gpart, Ghi, Glo, vb_g, t2_g,
                                                   srow, Wg, Wghi, Wglo, PTthi, PTtlo,
                                                   W2hi, W2lo, Wgs, sPTv, wgb, vpt, dvec,
                                                   bn_gamma, bn_beta, bn_mean, bn_var,
                                                   Whi, Wlo, bias_out, at, out, cnt);
}

// Round 9
// 206.622 us; speedup vs baseline: 2.7128x; 2.7128x over previous
//
#include <hip/hip_runtime.h>
#include <hip/hip_bf16.h>

#define NSP 4096   // H*W
#define CCH 256    // C
#define CIN 128    // Ci
#define BN_EPS 1e-5f

typedef __bf16 bf16x8 __attribute__((ext_vector_type(8)));
typedef __bf16 bf16x4 __attribute__((ext_vector_type(4)));
typedef float f32x4 __attribute__((ext_vector_type(4)));

// ================= fp32 tile helpers (prep only) =================================

__device__ __forceinline__ float4 fetch_tr(const float* __restrict__ A, int lda, int m0,
                                           int k0, int tid) {
  const int r = tid >> 2, kq = (tid & 3) << 2;
  return *(const float4*)(A + (size_t)(m0 + r) * lda + k0 + kq);
}
__device__ __forceinline__ void stash_tr(float (*As)[68], float4 v, int tid) {
  const int r = tid >> 2, kq = (tid & 3) << 2;
  As[kq + 0][r] = v.x; As[kq + 1][r] = v.y; As[kq + 2][r] = v.z; As[kq + 3][r] = v.w;
}
__device__ __forceinline__ float4 fetch_dir(const float* __restrict__ B, int ldb, int k0,
                                            int n0, int tid) {
  const int kr = tid >> 4, nq = (tid & 15) << 2;
  return *(const float4*)(B + (size_t)(k0 + kr) * ldb + n0 + nq);
}
__device__ __forceinline__ void stash_dir(float (*Bs)[68], float4 v, int tid) {
  const int kr = tid >> 4, nq = (tid & 15) << 2;
  *(float4*)(&Bs[kr][nq]) = v;
}

__device__ __forceinline__ void mm16(const float (*As)[68], const float (*Bs)[68],
                                     float acc[4][4], int ty, int tx) {
#pragma unroll
  for (int kk = 0; kk < 16; ++kk) {
    const float4 av = *(const float4*)(&As[kk][ty << 2]);
    const float4 bv = *(const float4*)(&Bs[kk][tx << 2]);
    const float ar[4] = {av.x, av.y, av.z, av.w};
    const float br[4] = {bv.x, bv.y, bv.z, bv.w};
#pragma unroll
    for (int i = 0; i < 4; ++i)
#pragma unroll
      for (int j = 0; j < 4; ++j) acc[i][j] += ar[i] * br[j];
  }
}

__device__ __forceinline__ float wave_reduce(float v) {
#pragma unroll
  for (int off = 32; off; off >>= 1) v += __shfl_down(v, off);
  return v;  // valid in lane 0
}

// ===== setup grid 2086: cast_b(0..1023) + prep(1024..1055) + cast_a(1056..2079)
// ===== + vb/d1(2080) + vpt(2081) + wgb(2082..2085)
__global__ __launch_bounds__(256) void setup_kernel(
    const float* __restrict__ bin, __bf16* __restrict__ bhi, __bf16* __restrict__ blo,
    float* __restrict__ srow, const float* __restrict__ W_w, const float* __restrict__ g_w,
    const float* __restrict__ phi_w, const float* __restrict__ theta_w,
    float* __restrict__ Wg, __bf16* __restrict__ Wghi, __bf16* __restrict__ Wglo,
    __bf16* __restrict__ PTthi, __bf16* __restrict__ PTtlo,
    const float* __restrict__ a, __bf16* __restrict__ at,
    const float* __restrict__ phi_b, const float* __restrict__ theta_b,
    const float* __restrict__ g_b,
    float* __restrict__ vb_g, float* __restrict__ vpt, float* __restrict__ wgb,
    float* __restrict__ dvec) {
  __shared__ float smem[64 * 68];
  const int idx = blockIdx.x;
  const int t = threadIdx.x;
  const int wave = t >> 6, lane = t & 63;
  if (idx < 1024) {
    // ---- cast b row -> bf16 hi/lo + exact fp32 row sum ----
    const int row = idx;
    const float* src = bin + (size_t)row * NSP + t * 16;
    float sum = 0.f;
    __bf16 hi[16], lo[16];
#pragma unroll
    for (int i = 0; i < 4; ++i) {
      const float4 v = *(const float4*)(src + i * 4);
      const float vv[4] = {v.x, v.y, v.z, v.w};
#pragma unroll
      for (int j = 0; j < 4; ++j) {
        const float x = vv[j];
        sum += x;
        const __bf16 h = (__bf16)x;
        hi[i * 4 + j] = h;
        lo[i * 4 + j] = (__bf16)(x - (float)h);
      }
    }
    __bf16* dh = bhi + (size_t)row * NSP + t * 16;
    __bf16* dl = blo + (size_t)row * NSP + t * 16;
    *(bf16x8*)dh = *(bf16x8*)&hi[0];
    *(bf16x8*)(dh + 8) = *(bf16x8*)&hi[8];
    *(bf16x8*)dl = *(bf16x8*)&lo[0];
    *(bf16x8*)(dl + 8) = *(bf16x8*)&lo[8];
#pragma unroll
    for (int off = 32; off; off >>= 1) sum += __shfl_down(sum, off);
    if ((t & 63) == 0) smem[t >> 6] = sum;
    __syncthreads();
    if (t == 0) srow[row] = smem[0] + smem[1] + smem[2] + smem[3];
  } else if (idx < 1056) {
    // ---- prep: Wg = W_w @ g_w (z=0, fp32+hi/lo) ; PTt = theta_w^T @ phi_w (z=1)
    const int p = idx - 1024;
    const int zsel = p >> 4, rem = p & 15;
    const int m0 = (rem >> 2) * 64, n0 = (rem & 3) * 64;
    float (*As)[68] = (float(*)[68])smem;
    float (*Bs)[68] = (float(*)[68])(smem + 16 * 68);
    const int ty = t >> 4, tx = t & 15;
    float acc[4][4] = {};
    if (zsel == 0) {
      float4 ar = fetch_tr(W_w, CIN, m0, 0, t);
      float4 br = fetch_dir(g_w, CCH, 0, n0, t);
      for (int kt = 0; kt < 8; ++kt) {
        stash_tr(As, ar, t); stash_dir(Bs, br, t);
        __syncthreads();
        if (kt < 7) { ar = fetch_tr(W_w, CIN, m0, (kt + 1) * 16, t);
                      br = fetch_dir(g_w, CCH, (kt + 1) * 16, n0, t); }
        mm16(As, Bs, acc, ty, tx);
        __syncthreads();
      }
#pragma unroll
      for (int i = 0; i < 4; ++i) {
        const size_t off = (size_t)(m0 + (ty << 2) + i) * 256 + n0 + (tx << 2);
        *(float4*)(Wg + off) = make_float4(acc[i][0], acc[i][1], acc[i][2], acc[i][3]);
        __bf16 h4[4], l4[4];
#pragma unroll
        for (int j = 0; j < 4; ++j) {
          const __bf16 h = (__bf16)acc[i][j];
          h4[j] = h; l4[j] = (__bf16)(acc[i][j] - (float)h);
        }
        *(bf16x4*)(Wghi + off) = *(bf16x4*)h4;
        *(bf16x4*)(Wglo + off) = *(bf16x4*)l4;
      }
    } else {
      float4 ar = fetch_dir(theta_w, CCH, 0, m0, t);   // swapped: computes PT^T
      float4 br = fetch_dir(phi_w, CCH, 0, n0, t);
      for (int kt = 0; kt < 8; ++kt) {
        stash_dir(As, ar, t); stash_dir(Bs, br, t);
        __syncthreads();
        if (kt < 7) { ar = fetch_dir(theta_w, CCH, (kt + 1) * 16, m0, t);
                      br = fetch_dir(phi_w, CCH, (kt + 1) * 16, n0, t); }
        mm16(As, Bs, acc, ty, tx);
        __syncthreads();
      }
#pragma unroll
      for (int i = 0; i < 4; ++i) {
        const size_t off = (size_t)(m0 + (ty << 2) + i) * 256 + n0 + (tx << 2);
        __bf16 h4[4], l4[4];
#pragma unroll
        for (int j = 0; j < 4; ++j) {
          const __bf16 h = (__bf16)acc[i][j];
          h4[j] = h; l4[j] = (__bf16)(acc[i][j] - (float)h);
        }
        *(bf16x4*)(PTthi + off) = *(bf16x4*)h4;
        *(bf16x4*)(PTtlo + off) = *(bf16x4*)l4;
      }
    }
  } else if (idx < 2080) {
    // ---- cast a -> bf16 transposed: at[b][n][c] ----
    const int p = idx - 1056;
    const int n0 = (p & 63) * 64, c0 = ((p >> 6) & 3) * 64, b = p >> 8;
    float (*tile)[68] = (float(*)[68])smem;
    const int cr = t >> 4, nq = (t & 15) << 2;
    const float* src = a + ((size_t)(b * CCH + c0)) * NSP + n0;
#pragma unroll
    for (int s = 0; s < 4; ++s) {
      const float4 v = *(const float4*)(src + (size_t)(cr + s * 16) * NSP + nq);
      *(float4*)&tile[cr + s * 16][nq] = v;
    }
    __syncthreads();
    const int n = t >> 2, cq = (t & 3) << 4;
    __bf16 outv[16];
#pragma unroll
    for (int i = 0; i < 16; ++i) outv[i] = (__bf16)tile[cq + i][n];
    __bf16* dst = at + ((size_t)(b * NSP + n0 + n)) * CCH + c0 + cq;
    *(bf16x8*)dst = *(bf16x8*)&outv[0];
    *(bf16x8*)(dst + 8) = *(bf16x8*)&outv[8];
  } else if (idx == 2080) {
    // ---- vb[c] = phi_w^T @ theta_b ; d1 = phi_b . theta_b ----
    float* tb_s = smem;
    float* pb_s = smem + 128;
    if (t < 128) { tb_s[t] = theta_b[t]; pb_s[t] = phi_b[t]; }
    __syncthreads();
    float acc = 0.f;
#pragma unroll 8
    for (int i = 0; i < 128; ++i) acc += phi_w[(size_t)i * 256 + t] * tb_s[i];
    vb_g[t] = acc;
    if (t < 64) {
      float pv = pb_s[t] * tb_s[t] + pb_s[t + 64] * tb_s[t + 64];
      pv = wave_reduce(pv);
      if (t == 0) dvec[0] = pv;
    }
  } else if (idx == 2081) {
    // ---- vpt[c] = phi_b^T @ theta_w (coalesced cols) ----
    float* pb_s = smem;
    if (t < 128) pb_s[t] = phi_b[t];
    __syncthreads();
    float acc = 0.f;
#pragma unroll 8
    for (int i = 0; i < 128; ++i) acc += pb_s[i] * theta_w[(size_t)i * 256 + t];
    vpt[t] = acc;
  } else {
    // ---- wgb[o] = W_w[o] . g_b : 4 blocks x 64 outputs ----
    const int p = idx - 2082;
    float* gb_s = smem;
    if (t < 128) gb_s[t] = g_b[t];
    __syncthreads();
    const float2 gv = *(const float2*)&gb_s[lane * 2];
    for (int i = 0; i < 16; ++i) {
      const int o = p * 64 + wave * 16 + i;
      const float2 r = *(const float2*)(W_w + (size_t)o * 128 + lane * 2);
      float v = fmaf(r.x, gv.x, r.y * gv.y);
      v = wave_reduce(v);
      if (lane == 0) wgb[o] = v;
    }
  }
}

// ================= gram partials: Gpart[kc][b] = B_b[:,kc] B_b[:,kc]^T ===========
__global__ __launch_bounds__(256) void gram_mfma_kernel(const __bf16* __restrict__ bhi,
                                                        const __bf16* __restrict__ blo,
                                                        float* __restrict__ Gpart) {
  const int jt = blockIdx.x, it = blockIdx.y;
  const int batch = blockIdx.z >> 4, kc = blockIdx.z & 15;
  const int wave = threadIdx.x >> 6, lane = threadIdx.x & 63;
  const int m = lane & 15, q = lane >> 4;
  const size_t base = (size_t)batch * CCH * NSP;
  const size_t arow = base + (size_t)(it * 64 + wave * 16 + m) * NSP + kc * 256 + q * 8;
  const size_t brow = base + (size_t)(jt * 64 + m) * NSP + kc * 256 + q * 8;
  f32x4 acc[4] = {};
#pragma unroll
  for (int ks = 0; ks < 8; ++ks) {
    const int k = ks * 32;
    const bf16x8 ah = *(const bf16x8*)(bhi + arow + k);
    const bf16x8 al = *(const bf16x8*)(blo + arow + k);
#pragma unroll
    for (int t4 = 0; t4 < 4; ++t4) {
      const size_t boff = brow + (size_t)t4 * 16 * NSP + k;
      const bf16x8 bh = *(const bf16x8*)(bhi + boff);
      const bf16x8 bl = *(const bf16x8*)(blo + boff);
      acc[t4] = __builtin_amdgcn_mfma_f32_16x16x32_bf16(ah, bh, acc[t4], 0, 0, 0);
      acc[t4] = __builtin_amdgcn_mfma_f32_16x16x32_bf16(ah, bl, acc[t4], 0, 0, 0);
      acc[t4] = __builtin_amdgcn_mfma_f32_16x16x32_bf16(al, bh, acc[t4], 0, 0, 0);
    }
  }
  float* Gp = Gpart + ((size_t)(kc * 4 + batch)) * 65536;
#pragma unroll
  for (int t4 = 0; t4 < 4; ++t4)
#pragma unroll
    for (int r = 0; r < 4; ++r)
      Gp[(size_t)(it * 64 + wave * 16 + q * 4 + r) * 256 + jt * 64 + t4 * 16 + m] =
          acc[t4][r];
}

// ===== redw2: fused reduce+w2 (blocks 0..255) + aux Wgs/sPTv/d2 (256..319) =======
// Main block (b, nt, mt4): reduces G[b] rows nt*16..+16 from the 16 partials into
// LDS (bf16 hi/lo), emits t2 rows (mt4==0), then computes 4 W2 tiles per wave.
// No global sync needed: the row partition exactly covers each tile's B-operand.
__global__ __launch_bounds__(256) void redw2_kernel(
    const float* __restrict__ Gpart, const float* __restrict__ vb_g,
    float* __restrict__ t2_g, const float* __restrict__ srow,
    const float* __restrict__ Wg,
    const __bf16* __restrict__ Wghi, const __bf16* __restrict__ Wglo,
    const __bf16* __restrict__ PTthi, const __bf16* __restrict__ PTtlo,
    __bf16* __restrict__ W2hi, __bf16* __restrict__ W2lo,
    float* __restrict__ Wgs, float* __restrict__ sPTv, float* __restrict__ dvec) {
  const int blk = blockIdx.x;
  const int t = threadIdx.x;
  const int wave = t >> 6, lane = t & 63;
  __shared__ __bf16 Gsh[16][264], Gsl[16][264];   // +8 pad: 2-way banks only
  __shared__ float lds[256];
  if (blk < 256) {
    const int b = blk >> 6, rem = blk & 63;
    const int nt = rem >> 2, mt4 = rem & 3;
    // ---- phase A: reduce 16 rows x 256 cols over 16 partials ----
    const int rr = t >> 4;              // row 0..15
    const int c0 = (t & 15) * 16;       // col chunk
    f32x4 s[4] = {};
#pragma unroll
    for (int p = 0; p < 16; ++p) {
      const float* src = Gpart + (((size_t)(p * 4 + b)) << 16) +
                         (size_t)(nt * 16 + rr) * 256 + c0;
#pragma unroll
      for (int e = 0; e < 4; ++e) s[e] += *(const f32x4*)(src + e * 4);
    }
    // t2 partial: dot row chunk with vb (only mt4==0 blocks write)
    if (mt4 == 0) {
      float part = 0.f;
#pragma unroll
      for (int e = 0; e < 4; ++e) {
        const float4 vv = *(const float4*)(vb_g + c0 + e * 4);
        part += s[e][0] * vv.x + s[e][1] * vv.y + s[e][2] * vv.z + s[e][3] * vv.w;
      }
#pragma unroll
      for (int off = 8; off; off >>= 1) part += __shfl_down(part, off);
      if ((t & 15) == 0) t2_g[b * 256 + nt * 16 + rr] = part;
    }
    // cast to hi/lo into LDS
    __bf16 h8[16], l8[16];
#pragma unroll
    for (int e = 0; e < 16; ++e) {
      const float x = s[e >> 2][e & 3];
      const __bf16 h = (__bf16)x;
      h8[e] = h; l8[e] = (__bf16)(x - (float)h);
    }
    *(bf16x8*)&Gsh[rr][c0] = *(bf16x8*)&h8[0];
    *(bf16x8*)&Gsh[rr][c0 + 8] = *(bf16x8*)&h8[8];
    *(bf16x8*)&Gsl[rr][c0] = *(bf16x8*)&l8[0];
    *(bf16x8*)&Gsl[rr][c0 + 8] = *(bf16x8*)&l8[8];
    __syncthreads();
    // ---- phase B: W2 tile (b, mt, nt), mt = mt4*4 + wave ----
    const int mt = mt4 * 4 + wave;
    const int m = lane & 15, q = lane >> 4;
    const __bf16* ah_p = Wghi + (size_t)(mt * 16 + m) * 256;
    const __bf16* al_p = Wglo + (size_t)(mt * 16 + m) * 256;
    f32x4 acc = {};
#pragma unroll
    for (int ks = 0; ks < 8; ++ks) {
      const int k = ks * 32 + q * 8;
      const bf16x8 bh = *(const bf16x8*)&Gsh[m][k];
      const bf16x8 bl = *(const bf16x8*)&Gsl[m][k];
      const bf16x8 ah = *(const bf16x8*)(ah_p + k);
      const bf16x8 al = *(const bf16x8*)(al_p + k);
      acc = __builtin_amdgcn_mfma_f32_16x16x32_bf16(ah, bh, acc, 0, 0, 0);
      acc = __builtin_amdgcn_mfma_f32_16x16x32_bf16(ah, bl, acc, 0, 0, 0);
      acc = __builtin_amdgcn_mfma_f32_16x16x32_bf16(al, bh, acc, 0, 0, 0);
    }
#pragma unroll
    for (int r = 0; r < 4; ++r) {
      const size_t off = ((size_t)b << 16) + (size_t)(mt * 16 + q * 4 + r) * 256 +
                         nt * 16 + m;
      const float v = acc[r];
      const __bf16 h = (__bf16)v;
      W2hi[off] = h;
      W2lo[off] = (__bf16)(v - (float)h);
    }
  } else {
    // ---- aux: Wgs = Wg@s ; sPTv = PTt@s ; d2 = s.vb ----
    const int p = blk - 256;
    const int b = p >> 4, seg = p & 15;
    lds[t] = srow[b * 256 + t];
    __syncthreads();
    const float4 sv = *(const float4*)&lds[lane * 4];
    for (int i = wave; i < 16; i += 4) {
      const int o = seg * 16 + i;
      const float4 r = *(const float4*)(Wg + (size_t)o * 256 + lane * 4);
      float v = fmaf(r.x, sv.x, fmaf(r.y, sv.y, fmaf(r.z, sv.z, r.w * sv.w)));
      v = wave_reduce(v);
      if (lane == 0) Wgs[b * 256 + o] = v;
    }
    for (int i = wave; i < 16; i += 4) {
      const int c = seg * 16 + i;
      const bf16x4 ph = *(const bf16x4*)(PTthi + (size_t)c * 256 + lane * 4);
      const bf16x4 pl = *(const bf16x4*)(PTtlo + (size_t)c * 256 + lane * 4);
      const float svv[4] = {sv.x, sv.y, sv.z, sv.w};
      float v = 0.f;
#pragma unroll
      for (int e = 0; e < 4; ++e) v += ((float)ph[e] + (float)pl[e]) * svv[e];
      v = wave_reduce(v);
      if (lane == 0) sPTv[b * 256 + c] = v;
    }
    if (seg == 0 && wave == 0) {
      const float4 vbv = *(const float4*)(vb_g + lane * 4);
      float v = fmaf(vbv.x, sv.x, fmaf(vbv.y, sv.y, fmaf(vbv.z, sv.z, vbv.w * sv.w)));
      v = wave_reduce(v);
      if (lane == 0) dvec[1 + b] = v;
    }
  }
}

// ===== W_out = scale*((W2@PT + rank1)/N + rank1') (0..255) + bias chain (256..271)
__global__ __launch_bounds__(256) void wout_mfma_kernel(
    const __bf16* __restrict__ W2hi, const __bf16* __restrict__ W2lo,
    const __bf16* __restrict__ PTthi, const __bf16* __restrict__ PTtlo,
    const float* __restrict__ Wgs, const float* __restrict__ sPT,
    const float* __restrict__ wgb, const float* __restrict__ vpt,
    const float* __restrict__ Wg, const float* __restrict__ t2_g,
    const float* __restrict__ dvec,
    const float* __restrict__ bn_gamma, const float* __restrict__ bn_beta,
    const float* __restrict__ bn_mean, const float* __restrict__ bn_var,
    __bf16* __restrict__ Whi, __bf16* __restrict__ Wlo,
    float* __restrict__ bias_out) {
  const int blk = blockIdx.x;
  const int t = threadIdx.x;
  const int wave = t >> 6, lane = t & 63;
  if (blk < 256) {
    const int tile = blk * 4 + wave;
    const int batch = tile >> 8, rem = tile & 255;
    const int mt = rem >> 4, nt = rem & 15;
    const int m = lane & 15, q = lane >> 4;
    const __bf16* ah_p = W2hi + (size_t)batch * 65536 + (size_t)(mt * 16 + m) * 256;
    const __bf16* al_p = W2lo + (size_t)batch * 65536 + (size_t)(mt * 16 + m) * 256;
    const __bf16* bh_p = PTthi + (size_t)(nt * 16 + m) * 256;   // PTt row = PT column
    const __bf16* bl_p = PTtlo + (size_t)(nt * 16 + m) * 256;
    f32x4 acc = {};
#pragma unroll
    for (int ks = 0; ks < 8; ++ks) {
      const int k = ks * 32 + q * 8;
      const bf16x8 ah = *(const bf16x8*)(ah_p + k);
      const bf16x8 al = *(const bf16x8*)(al_p + k);
      const bf16x8 bh = *(const bf16x8*)(bh_p + k);
      const bf16x8 bl = *(const bf16x8*)(bl_p + k);
      acc = __builtin_amdgcn_mfma_f32_16x16x32_bf16(ah, bh, acc, 0, 0, 0);
      acc = __builtin_amdgcn_mfma_f32_16x16x32_bf16(ah, bl, acc, 0, 0, 0);
      acc = __builtin_amdgcn_mfma_f32_16x16x32_bf16(al, bh, acc, 0, 0, 0);
    }
    const float invN = 1.0f / 4096.0f;
    const int c = nt * 16 + m;
    const float vpt_c = vpt[c];
    const float sPT_c = sPT[batch * 256 + c];
#pragma unroll
    for (int r = 0; r < 4; ++r) {
      const int o = mt * 16 + q * 4 + r;
      const float sc = bn_gamma[o] * rsqrtf(bn_var[o] + BN_EPS);
      const float w = sc * ((acc[r] + Wgs[batch * 256 + o] * vpt_c + wgb[o] * sPT_c) * invN +
                            wgb[o] * vpt_c);
      const size_t off = (size_t)batch * 65536 + (size_t)o * 256 + c;
      const __bf16 h = (__bf16)w;
      Whi[off] = h;
      Wlo[off] = (__bf16)(w - (float)h);
    }
  } else {
    // ---- bias chain: bias = sc*((Wg@t2 + Wgs*d1 + wgb*(d2+N*d1))/N - mean)+beta
    const int p = blk - 256;
    const int b = p >> 2, quarter = p & 3;
    __shared__ float t2s[256];
    t2s[t] = t2_g[b * 256 + t];
    __syncthreads();
    const float d1 = dvec[0], d2 = dvec[1 + b];
    const float invN = 1.0f / 4096.0f;
    const float4 tv = *(const float4*)&t2s[lane * 4];
    for (int it = 0; it < 16; ++it) {
      const int o = quarter * 64 + wave * 16 + it;
      const float4 r = *(const float4*)(Wg + (size_t)o * 256 + lane * 4);
      float v = fmaf(r.x, tv.x, fmaf(r.y, tv.y, fmaf(r.z, tv.z, r.w * tv.w)));
      v = wave_reduce(v);
      if (lane == 0) {
        const float bias_full = (v + Wgs[b * 256 + o] * d1 +
                                 wgb[o] * (d2 + 4096.0f * d1)) * invN;
        const float sc = bn_gamma[o] * rsqrtf(bn_var[o] + BN_EPS);
        bias_out[b * 256 + o] = sc * (bias_full - bn_mean[o]) + bn_beta[o];
      }
    }
  }
}

// ================= out[b] = W_out[b] @ a[b] + bias (MFMA, 32-wide n-tiles) =======
__global__ __launch_bounds__(256) void out_mfma_kernel(const __bf16* __restrict__ Whi,
                                                       const __bf16* __restrict__ Wlo,
                                                       const __bf16* __restrict__ at,
                                                       const float* __restrict__ bias_out,
                                                       float* __restrict__ out) {
  const int nt = blockIdx.x, mt = blockIdx.y, b = blockIdx.z;
  const int wave = threadIdx.x >> 6, lane = threadIdx.x & 63;
  const int m = lane & 15, q = lane >> 4;
  const int o = mt * 64 + wave * 16 + m;
  const __bf16* wh = Whi + (size_t)b * 65536 + (size_t)o * 256;
  const __bf16* wl = Wlo + (size_t)b * 65536 + (size_t)o * 256;
  const __bf16* atb = at + ((size_t)b * NSP + nt * 32) * CCH;
  f32x4 acc[2] = {};
#pragma unroll
  for (int ks = 0; ks < 8; ++ks) {
    const int k = ks * 32 + q * 8;
    const bf16x8 ah = *(const bf16x8*)(wh + k);
    const bf16x8 al = *(const bf16x8*)(wl + k);
#pragma unroll
    for (int t4 = 0; t4 < 2; ++t4) {
      const bf16x8 bh = *(const bf16x8*)(atb + (size_t)(t4 * 16 + m) * 256 + k);
      acc[t4] = __builtin_amdgcn_mfma_f32_16x16x32_bf16(ah, bh, acc[t4], 0, 0, 0);
      acc[t4] = __builtin_amdgcn_mfma_f32_16x16x32_bf16(al, bh, acc[t4], 0, 0, 0);
    }
  }
  float* ob = out + (size_t)b * CCH * NSP;
#pragma unroll
  for (int r = 0; r < 4; ++r) {
    const int orow = mt * 64 + wave * 16 + q * 4 + r;
    const float bo = bias_out[b * 256 + orow];
#pragma unroll
    for (int t4 = 0; t4 < 2; ++t4)
      ob[(size_t)orow * NSP + nt * 32 + t4 * 16 + m] = acc[t4][r] + bo;
  }
}

extern "C" void kernel_launch(void* const* d_in, const int* in_sizes, int n_in,
                              void* d_out, int out_size, void* d_ws, size_t ws_size,
                              hipStream_t stream) {
  (void)in_sizes; (void)n_in; (void)out_size; (void)ws_size;
  const float* a       = (const float*)d_in[0];
  const float* bI      = (const float*)d_in[1];
  const float* theta_w = (const float*)d_in[2];
  const float* theta_b = (const float*)d_in[3];
  const float* phi_w   = (const float*)d_in[4];
  const float* phi_b   = (const float*)d_in[5];
  const float* g_w     = (const float*)d_in[6];
  const float* g_b     = (const float*)d_in[7];
  const float* W_w     = (const float*)d_in[8];
  const float* bn_gamma= (const float*)d_in[9];
  const float* bn_beta = (const float*)d_in[10];
  const float* bn_mean = (const float*)d_in[11];
  const float* bn_var  = (const float*)d_in[12];
  float* out = (float*)d_out;
  float* ws  = (float*)d_ws;

  // fp32 region (float offsets)
  float* Gpart    = ws;                  // 4194304 (16 MB)
  float* srow     = ws + 4194304;        // 1024
  float* Wg       = ws + 4195328;        // 65536
  float* bias_out = ws + 4260864;        // 1024
  float* Wgs      = ws + 4261888;        // 1024
  float* sPTv     = ws + 4262912;        // 1024
  float* wgb      = ws + 4263936;        // 256
  float* vpt      = ws + 4264192;        // 256
  float* vb_g     = ws + 4264448;        // 256
  float* t2_g     = ws + 4264704;        // 1024
  float* dvec     = ws + 4265728;        // 8
  // bf16 region
  __bf16* bhi   = (__bf16*)(ws + 4265984);   // 8 MB
  __bf16* blo   = (__bf16*)(ws + 6363136);   // 8 MB
  __bf16* at    = (__bf16*)(ws + 8460288);   // 8 MB
  __bf16* Wghi  = (__bf16*)(ws + 10557440);  // 128 KB each below
  __bf16* Wglo  = (__bf16*)(ws + 10590208);
  __bf16* PTthi = (__bf16*)(ws + 10622976);
  __bf16* PTtlo = (__bf16*)(ws + 10655744);
  __bf16* W2hi  = (__bf16*)(ws + 10688512);  // 512 KB each below
  __bf16* W2lo  = (__bf16*)(ws + 10819584);
  __bf16* Whi   = (__bf16*)(ws + 10950656);
  __bf16* Wlo   = (__bf16*)(ws + 11081728); // end ~44.9 MB

  setup_kernel<<<dim3(2086), dim3(256), 0, stream>>>(bI, bhi, blo, srow, W_w, g_w, phi_w,
                                                     theta_w, Wg, Wghi, Wglo, PTthi, PTtlo,
                                                     a, at, phi_b, theta_b, g_b,
                                                     vb_g, vpt, wgb, dvec);
  gram_mfma_kernel<<<dim3(4, 4, 64), dim3(256), 0, stream>>>(bhi, blo, Gpart);
  redw2_kernel<<<dim3(320), dim3(256), 0, stream>>>(Gpart, vb_g, t2_g, srow, Wg,
                                                    Wghi, Wglo, PTthi, PTtlo,
                                                    W2hi, W2lo, Wgs, sPTv, dvec);
  wout_mfma_kernel<<<dim3(272), dim3(256), 0, stream>>>(W2hi, W2lo, PTthi, PTtlo,
                                                        Wgs, sPTv, wgb, vpt, Wg, t2_g,
                                                        dvec, bn_gamma, bn_beta, bn_mean,
                                                        bn_var, Whi, Wlo, bias_out);
  out_mfma_kernel<<<dim3(128, 4, 4), dim3(256), 0, stream>>>(Whi, Wlo, at, bias_out, out);
}

// Round 10
// 197.402 us; speedup vs baseline: 2.8395x; 1.0467x over previous
//
#include <hip/hip_runtime.h>
#include <hip/hip_bf16.h>

#define NSP 4096   // H*W
#define CCH 256    // C
#define CIN 128    // Ci
#define BN_EPS 1e-5f

typedef __bf16 bf16x8 __attribute__((ext_vector_type(8)));
typedef __bf16 bf16x4 __attribute__((ext_vector_type(4)));
typedef float f32x4 __attribute__((ext_vector_type(4)));
typedef unsigned short u16x8 __attribute__((ext_vector_type(8)));

// ================= fp32 tile helpers (prep only) =================================

__device__ __forceinline__ float4 fetch_tr(const float* __restrict__ A, int lda, int m0,
                                           int k0, int tid) {
  const int r = tid >> 2, kq = (tid & 3) << 2;
  return *(const float4*)(A + (size_t)(m0 + r) * lda + k0 + kq);
}
__device__ __forceinline__ void stash_tr(float (*As)[68], float4 v, int tid) {
  const int r = tid >> 2, kq = (tid & 3) << 2;
  As[kq + 0][r] = v.x; As[kq + 1][r] = v.y; As[kq + 2][r] = v.z; As[kq + 3][r] = v.w;
}
__device__ __forceinline__ float4 fetch_dir(const float* __restrict__ B, int ldb, int k0,
                                            int n0, int tid) {
  const int kr = tid >> 4, nq = (tid & 15) << 2;
  return *(const float4*)(B + (size_t)(k0 + kr) * ldb + n0 + nq);
}
__device__ __forceinline__ void stash_dir(float (*Bs)[68], float4 v, int tid) {
  const int kr = tid >> 4, nq = (tid & 15) << 2;
  *(float4*)(&Bs[kr][nq]) = v;
}

__device__ __forceinline__ void mm16(const float (*As)[68], const float (*Bs)[68],
                                     float acc[4][4], int ty, int tx) {
#pragma unroll
  for (int kk = 0; kk < 16; ++kk) {
    const float4 av = *(const float4*)(&As[kk][ty << 2]);
    const float4 bv = *(const float4*)(&Bs[kk][tx << 2]);
    const float ar[4] = {av.x, av.y, av.z, av.w};
    const float br[4] = {bv.x, bv.y, bv.z, bv.w};
#pragma unroll
    for (int i = 0; i < 4; ++i)
#pragma unroll
      for (int j = 0; j < 4; ++j) acc[i][j] += ar[i] * br[j];
  }
}

__device__ __forceinline__ float wave_reduce(float v) {
#pragma unroll
  for (int off = 32; off; off >>= 1) v += __shfl_down(v, off);
  return v;  // valid in lane 0
}

// in-register fp32x8 -> bf16 hi/lo (truncation; pair error ~2^-16 relative)
__device__ __forceinline__ void f8_hilo(const float* __restrict__ p,
                                        bf16x8& h, bf16x8& l) {
  const float4 v0 = *(const float4*)p;
  const float4 v1 = *(const float4*)(p + 4);
  const float vv[8] = {v0.x, v0.y, v0.z, v0.w, v1.x, v1.y, v1.z, v1.w};
  u16x8 hu, lu;
#pragma unroll
  for (int e = 0; e < 8; ++e) {
    const unsigned u = __float_as_uint(vv[e]);
    hu[e] = (unsigned short)(u >> 16);
    const float hf = __uint_as_float(u & 0xffff0000u);
    lu[e] = (unsigned short)(__float_as_uint(vv[e] - hf) >> 16);
  }
  h = *(bf16x8*)&hu;
  l = *(bf16x8*)&lu;
}

// ===== front grid 3110: gram(0..1023) + cast_a(1024..2047) + srow(2048..3071)
// ===== + prep(3072..3103) + vb/d1(3104) + vpt(3105) + wgb(3106..3109)
// All blocks mutually independent -> one dispatch, machine-wide overlap.
__global__ __launch_bounds__(256) void front_kernel(
    const float* __restrict__ bin, const float* __restrict__ a,
    const float* __restrict__ W_w, const float* __restrict__ g_w,
    const float* __restrict__ phi_w, const float* __restrict__ theta_w,
    const float* __restrict__ phi_b, const float* __restrict__ theta_b,
    const float* __restrict__ g_b,
    float* __restrict__ Gpart, float* __restrict__ srow,
    float* __restrict__ Wg, __bf16* __restrict__ Wghi, __bf16* __restrict__ Wglo,
    __bf16* __restrict__ PTthi, __bf16* __restrict__ PTtlo,
    __bf16* __restrict__ at,
    float* __restrict__ vb_g, float* __restrict__ vpt, float* __restrict__ wgb,
    float* __restrict__ dvec) {
  __shared__ float smem[64 * 68];
  const int idx = blockIdx.x;
  const int t = threadIdx.x;
  const int wave = t >> 6, lane = t & 63;
  if (idx < 1024) {
    // ---- gram partials from fp32 b directly (in-register hi/lo split) ----
    const int jt = idx & 3, it = (idx >> 2) & 3;
    const int z = idx >> 4, batch = z >> 4, kc = z & 15;
    const int m = lane & 15, q = lane >> 4;
    const float* base = bin + (size_t)batch * CCH * NSP;
    const float* arow = base + (size_t)(it * 64 + wave * 16 + m) * NSP + kc * 256 + q * 8;
    const float* brow = base + (size_t)(jt * 64 + m) * NSP + kc * 256 + q * 8;
    f32x4 acc[4] = {};
#pragma unroll
    for (int ks = 0; ks < 8; ++ks) {
      const int k = ks * 32;
      bf16x8 ah, al;
      f8_hilo(arow + k, ah, al);
#pragma unroll
      for (int t4 = 0; t4 < 4; ++t4) {
        bf16x8 bh, bl;
        f8_hilo(brow + (size_t)t4 * 16 * NSP + k, bh, bl);
        acc[t4] = __builtin_amdgcn_mfma_f32_16x16x32_bf16(ah, bh, acc[t4], 0, 0, 0);
        acc[t4] = __builtin_amdgcn_mfma_f32_16x16x32_bf16(ah, bl, acc[t4], 0, 0, 0);
        acc[t4] = __builtin_amdgcn_mfma_f32_16x16x32_bf16(al, bh, acc[t4], 0, 0, 0);
      }
    }
    float* Gp = Gpart + ((size_t)(kc * 4 + batch)) * 65536;
#pragma unroll
    for (int t4 = 0; t4 < 4; ++t4)
#pragma unroll
      for (int r = 0; r < 4; ++r)
        Gp[(size_t)(it * 64 + wave * 16 + q * 4 + r) * 256 + jt * 64 + t4 * 16 + m] =
            acc[t4][r];
  } else if (idx < 2048) {
    // ---- cast a -> bf16 transposed: at[b][n][c] ----
    const int p = idx - 1024;
    const int n0 = (p & 63) * 64, c0 = ((p >> 6) & 3) * 64, b = p >> 8;
    float (*tile)[68] = (float(*)[68])smem;
    const int cr = t >> 4, nq = (t & 15) << 2;
    const float* src = a + ((size_t)(b * CCH + c0)) * NSP + n0;
#pragma unroll
    for (int s = 0; s < 4; ++s) {
      const float4 v = *(const float4*)(src + (size_t)(cr + s * 16) * NSP + nq);
      *(float4*)&tile[cr + s * 16][nq] = v;
    }
    __syncthreads();
    const int n = t >> 2, cq = (t & 3) << 4;
    __bf16 outv[16];
#pragma unroll
    for (int i = 0; i < 16; ++i) outv[i] = (__bf16)tile[cq + i][n];
    __bf16* dst = at + ((size_t)(b * NSP + n0 + n)) * CCH + c0 + cq;
    *(bf16x8*)dst = *(bf16x8*)&outv[0];
    *(bf16x8*)(dst + 8) = *(bf16x8*)&outv[8];
  } else if (idx < 3072) {
    // ---- srow: exact fp32 row sum of b ----
    const int row = idx - 2048;
    const float* src = bin + (size_t)row * NSP + t * 16;
    float sum = 0.f;
#pragma unroll
    for (int i = 0; i < 4; ++i) {
      const float4 v = *(const float4*)(src + i * 4);
      sum += v.x + v.y + v.z + v.w;
    }
#pragma unroll
    for (int off = 32; off; off >>= 1) sum += __shfl_down(sum, off);
    if ((t & 63) == 0) smem[t >> 6] = sum;
    __syncthreads();
    if (t == 0) srow[row] = smem[0] + smem[1] + smem[2] + smem[3];
  } else if (idx < 3104) {
    // ---- prep: Wg = W_w @ g_w (z=0, fp32+hi/lo) ; PTt = theta_w^T @ phi_w (z=1)
    const int p = idx - 3072;
    const int zsel = p >> 4, rem = p & 15;
    const int m0 = (rem >> 2) * 64, n0 = (rem & 3) * 64;
    float (*As)[68] = (float(*)[68])smem;
    float (*Bs)[68] = (float(*)[68])(smem + 16 * 68);
    const int ty = t >> 4, tx = t & 15;
    float acc[4][4] = {};
    if (zsel == 0) {
      float4 ar = fetch_tr(W_w, CIN, m0, 0, t);
      float4 br = fetch_dir(g_w, CCH, 0, n0, t);
      for (int kt = 0; kt < 8; ++kt) {
        stash_tr(As, ar, t); stash_dir(Bs, br, t);
        __syncthreads();
        if (kt < 7) { ar = fetch_tr(W_w, CIN, m0, (kt + 1) * 16, t);
                      br = fetch_dir(g_w, CCH, (kt + 1) * 16, n0, t); }
        mm16(As, Bs, acc, ty, tx);
        __syncthreads();
      }
#pragma unroll
      for (int i = 0; i < 4; ++i) {
        const size_t off = (size_t)(m0 + (ty << 2) + i) * 256 + n0 + (tx << 2);
        *(float4*)(Wg + off) = make_float4(acc[i][0], acc[i][1], acc[i][2], acc[i][3]);
        __bf16 h4[4], l4[4];
#pragma unroll
        for (int j = 0; j < 4; ++j) {
          const __bf16 h = (__bf16)acc[i][j];
          h4[j] = h; l4[j] = (__bf16)(acc[i][j] - (float)h);
        }
        *(bf16x4*)(Wghi + off) = *(bf16x4*)h4;
        *(bf16x4*)(Wglo + off) = *(bf16x4*)l4;
      }
    } else {
      float4 ar = fetch_dir(theta_w, CCH, 0, m0, t);   // swapped: computes PT^T
      float4 br = fetch_dir(phi_w, CCH, 0, n0, t);
      for (int kt = 0; kt < 8; ++kt) {
        stash_dir(As, ar, t); stash_dir(Bs, br, t);
        __syncthreads();
        if (kt < 7) { ar = fetch_dir(theta_w, CCH, (kt + 1) * 16, m0, t);
                      br = fetch_dir(phi_w, CCH, (kt + 1) * 16, n0, t); }
        mm16(As, Bs, acc, ty, tx);
        __syncthreads();
      }
#pragma unroll
      for (int i = 0; i < 4; ++i) {
        const size_t off = (size_t)(m0 + (ty << 2) + i) * 256 + n0 + (tx << 2);
        __bf16 h4[4], l4[4];
#pragma unroll
        for (int j = 0; j < 4; ++j) {
          const __bf16 h = (__bf16)acc[i][j];
          h4[j] = h; l4[j] = (__bf16)(acc[i][j] - (float)h);
        }
        *(bf16x4*)(PTthi + off) = *(bf16x4*)h4;
        *(bf16x4*)(PTtlo + off) = *(bf16x4*)l4;
      }
    }
  } else if (idx == 3104) {
    // ---- vb[c] = phi_w^T @ theta_b ; d1 = phi_b . theta_b ----
    float* tb_s = smem;
    float* pb_s = smem + 128;
    if (t < 128) { tb_s[t] = theta_b[t]; pb_s[t] = phi_b[t]; }
    __syncthreads();
    float acc = 0.f;
#pragma unroll 8
    for (int i = 0; i < 128; ++i) acc += phi_w[(size_t)i * 256 + t] * tb_s[i];
    vb_g[t] = acc;
    if (t < 64) {
      float pv = pb_s[t] * tb_s[t] + pb_s[t + 64] * tb_s[t + 64];
      pv = wave_reduce(pv);
      if (t == 0) dvec[0] = pv;
    }
  } else if (idx == 3105) {
    // ---- vpt[c] = phi_b^T @ theta_w (coalesced cols) ----
    float* pb_s = smem;
    if (t < 128) pb_s[t] = phi_b[t];
    __syncthreads();
    float acc = 0.f;
#pragma unroll 8
    for (int i = 0; i < 128; ++i) acc += pb_s[i] * theta_w[(size_t)i * 256 + t];
    vpt[t] = acc;
  } else {
    // ---- wgb[o] = W_w[o] . g_b : 4 blocks x 64 outputs ----
    const int p = idx - 3106;
    float* gb_s = smem;
    if (t < 128) gb_s[t] = g_b[t];
    __syncthreads();
    const float2 gv = *(const float2*)&gb_s[lane * 2];
    for (int i = 0; i < 16; ++i) {
      const int o = p * 64 + wave * 16 + i;
      const float2 r = *(const float2*)(W_w + (size_t)o * 128 + lane * 2);
      float v = fmaf(r.x, gv.x, r.y * gv.y);
      v = wave_reduce(v);
      if (lane == 0) wgb[o] = v;
    }
  }
}

// ===== redw2: fused reduce+w2 (blocks 0..255) + aux Wgs/sPTv/d2 (256..319) =======
__global__ __launch_bounds__(256) void redw2_kernel(
    const float* __restrict__ Gpart, const float* __restrict__ vb_g,
    float* __restrict__ t2_g, const float* __restrict__ srow,
    const float* __restrict__ Wg,
    const __bf16* __restrict__ Wghi, const __bf16* __restrict__ Wglo,
    const __bf16* __restrict__ PTthi, const __bf16* __restrict__ PTtlo,
    __bf16* __restrict__ W2hi, __bf16* __restrict__ W2lo,
    float* __restrict__ Wgs, float* __restrict__ sPTv, float* __restrict__ dvec) {
  const int blk = blockIdx.x;
  const int t = threadIdx.x;
  const int wave = t >> 6, lane = t & 63;
  __shared__ __bf16 Gsh[16][264], Gsl[16][264];   // +8 pad: 2-way banks only
  __shared__ float lds[256];
  if (blk < 256) {
    const int b = blk >> 6, rem = blk & 63;
    const int nt = rem >> 2, mt4 = rem & 3;
    // ---- phase A: reduce 16 rows x 256 cols over 16 partials ----
    const int rr = t >> 4;
    const int c0 = (t & 15) * 16;
    f32x4 s[4] = {};
#pragma unroll
    for (int p = 0; p < 16; ++p) {
      const float* src = Gpart + (((size_t)(p * 4 + b)) << 16) +
                         (size_t)(nt * 16 + rr) * 256 + c0;
#pragma unroll
      for (int e = 0; e < 4; ++e) s[e] += *(const f32x4*)(src + e * 4);
    }
    if (mt4 == 0) {
      float part = 0.f;
#pragma unroll
      for (int e = 0; e < 4; ++e) {
        const float4 vv = *(const float4*)(vb_g + c0 + e * 4);
        part += s[e][0] * vv.x + s[e][1] * vv.y + s[e][2] * vv.z + s[e][3] * vv.w;
      }
#pragma unroll
      for (int off = 8; off; off >>= 1) part += __shfl_down(part, off);
      if ((t & 15) == 0) t2_g[b * 256 + nt * 16 + rr] = part;
    }
    __bf16 h8[16], l8[16];
#pragma unroll
    for (int e = 0; e < 16; ++e) {
      const float x = s[e >> 2][e & 3];
      const __bf16 h = (__bf16)x;
      h8[e] = h; l8[e] = (__bf16)(x - (float)h);
    }
    *(bf16x8*)&Gsh[rr][c0] = *(bf16x8*)&h8[0];
    *(bf16x8*)&Gsh[rr][c0 + 8] = *(bf16x8*)&h8[8];
    *(bf16x8*)&Gsl[rr][c0] = *(bf16x8*)&l8[0];
    *(bf16x8*)&Gsl[rr][c0 + 8] = *(bf16x8*)&l8[8];
    __syncthreads();
    // ---- phase B: W2 tile (b, mt, nt), mt = mt4*4 + wave ----
    const int mt = mt4 * 4 + wave;
    const int m = lane & 15, q = lane >> 4;
    const __bf16* ah_p = Wghi + (size_t)(mt * 16 + m) * 256;
    const __bf16* al_p = Wglo + (size_t)(mt * 16 + m) * 256;
    f32x4 acc = {};
#pragma unroll
    for (int ks = 0; ks < 8; ++ks) {
      const int k = ks * 32 + q * 8;
      const bf16x8 bh = *(const bf16x8*)&Gsh[m][k];
      const bf16x8 bl = *(const bf16x8*)&Gsl[m][k];
      const bf16x8 ah = *(const bf16x8*)(ah_p + k);
      const bf16x8 al = *(const bf16x8*)(al_p + k);
      acc = __builtin_amdgcn_mfma_f32_16x16x32_bf16(ah, bh, acc, 0, 0, 0);
      acc = __builtin_amdgcn_mfma_f32_16x16x32_bf16(ah, bl, acc, 0, 0, 0);
      acc = __builtin_amdgcn_mfma_f32_16x16x32_bf16(al, bh, acc, 0, 0, 0);
    }
#pragma unroll
    for (int r = 0; r < 4; ++r) {
      const size_t off = ((size_t)b << 16) + (size_t)(mt * 16 + q * 4 + r) * 256 +
                         nt * 16 + m;
      const float v = acc[r];
      const __bf16 h = (__bf16)v;
      W2hi[off] = h;
      W2lo[off] = (__bf16)(v - (float)h);
    }
  } else {
    // ---- aux: Wgs = Wg@s ; sPTv = PTt@s ; d2 = s.vb ----
    const int p = blk - 256;
    const int b = p >> 4, seg = p & 15;
    lds[t] = srow[b * 256 + t];
    __syncthreads();
    const float4 sv = *(const float4*)&lds[lane * 4];
    for (int i = wave; i < 16; i += 4) {
      const int o = seg * 16 + i;
      const float4 r = *(const float4*)(Wg + (size_t)o * 256 + lane * 4);
      float v = fmaf(r.x, sv.x, fmaf(r.y, sv.y, fmaf(r.z, sv.z, r.w * sv.w)));
      v = wave_reduce(v);
      if (lane == 0) Wgs[b * 256 + o] = v;
    }
    for (int i = wave; i < 16; i += 4) {
      const int c = seg * 16 + i;
      const bf16x4 ph = *(const bf16x4*)(PTthi + (size_t)c * 256 + lane * 4);
      const bf16x4 pl = *(const bf16x4*)(PTtlo + (size_t)c * 256 + lane * 4);
      const float svv[4] = {sv.x, sv.y, sv.z, sv.w};
      float v = 0.f;
#pragma unroll
      for (int e = 0; e < 4; ++e) v += ((float)ph[e] + (float)pl[e]) * svv[e];
      v = wave_reduce(v);
      if (lane == 0) sPTv[b * 256 + c] = v;
    }
    if (seg == 0 && wave == 0) {
      const float4 vbv = *(const float4*)(vb_g + lane * 4);
      float v = fmaf(vbv.x, sv.x, fmaf(vbv.y, sv.y, fmaf(vbv.z, sv.z, vbv.w * sv.w)));
      v = wave_reduce(v);
      if (lane == 0) dvec[1 + b] = v;
    }
  }
}

// ===== W_out = scale*((W2@PT + rank1)/N + rank1') (0..255) + bias chain (256..271)
__global__ __launch_bounds__(256) void wout_mfma_kernel(
    const __bf16* __restrict__ W2hi, const __bf16* __restrict__ W2lo,
    const __bf16* __restrict__ PTthi, const __bf16* __restrict__ PTtlo,
    const float* __restrict__ Wgs, const float* __restrict__ sPT,
    const float* __restrict__ wgb, const float* __restrict__ vpt,
    const float* __restrict__ Wg, const float* __restrict__ t2_g,
    const float* __restrict__ dvec,
    const float* __restrict__ bn_gamma, const float* __restrict__ bn_beta,
    const float* __restrict__ bn_mean, const float* __restrict__ bn_var,
    __bf16* __restrict__ Whi, __bf16* __restrict__ Wlo,
    float* __restrict__ bias_out) {
  const int blk = blockIdx.x;
  const int t = threadIdx.x;
  const int wave = t >> 6, lane = t & 63;
  if (blk < 256) {
    const int tile = blk * 4 + wave;
    const int batch = tile >> 8, rem = tile & 255;
    const int mt = rem >> 4, nt = rem & 15;
    const int m = lane & 15, q = lane >> 4;
    const __bf16* ah_p = W2hi + (size_t)batch * 65536 + (size_t)(mt * 16 + m) * 256;
    const __bf16* al_p = W2lo + (size_t)batch * 65536 + (size_t)(mt * 16 + m) * 256;
    const __bf16* bh_p = PTthi + (size_t)(nt * 16 + m) * 256;   // PTt row = PT column
    const __bf16* bl_p = PTtlo + (size_t)(nt * 16 + m) * 256;
    f32x4 acc = {};
#pragma unroll
    for (int ks = 0; ks < 8; ++ks) {
      const int k = ks * 32 + q * 8;
      const bf16x8 ah = *(const bf16x8*)(ah_p + k);
      const bf16x8 al = *(const bf16x8*)(al_p + k);
      const bf16x8 bh = *(const bf16x8*)(bh_p + k);
      const bf16x8 bl = *(const bf16x8*)(bl_p + k);
      acc = __builtin_amdgcn_mfma_f32_16x16x32_bf16(ah, bh, acc, 0, 0, 0);
      acc = __builtin_amdgcn_mfma_f32_16x16x32_bf16(ah, bl, acc, 0, 0, 0);
      acc = __builtin_amdgcn_mfma_f32_16x16x32_bf16(al, bh, acc, 0, 0, 0);
    }
    const float invN = 1.0f / 4096.0f;
    const int c = nt * 16 + m;
    const float vpt_c = vpt[c];
    const float sPT_c = sPT[batch * 256 + c];
#pragma unroll
    for (int r = 0; r < 4; ++r) {
      const int o = mt * 16 + q * 4 + r;
      const float sc = bn_gamma[o] * rsqrtf(bn_var[o] + BN_EPS);
      const float w = sc * ((acc[r] + Wgs[batch * 256 + o] * vpt_c + wgb[o] * sPT_c) * invN +
                            wgb[o] * vpt_c);
      const size_t off = (size_t)batch * 65536 + (size_t)o * 256 + c;
      const __bf16 h = (__bf16)w;
      Whi[off] = h;
      Wlo[off] = (__bf16)(w - (float)h);
    }
  } else {
    // ---- bias chain: bias = sc*((Wg@t2 + Wgs*d1 + wgb*(d2+N*d1))/N - mean)+beta
    const int p = blk - 256;
    const int b = p >> 2, quarter = p & 3;
    __shared__ float t2s[256];
    t2s[t] = t2_g[b * 256 + t];
    __syncthreads();
    const float d1 = dvec[0], d2 = dvec[1 + b];
    const float invN = 1.0f / 4096.0f;
    const float4 tv = *(const float4*)&t2s[lane * 4];
    for (int it = 0; it < 16; ++it) {
      const int o = quarter * 64 + wave * 16 + it;
      const float4 r = *(const float4*)(Wg + (size_t)o * 256 + lane * 4);
      float v = fmaf(r.x, tv.x, fmaf(r.y, tv.y, fmaf(r.z, tv.z, r.w * tv.w)));
      v = wave_reduce(v);
      if (lane == 0) {
        const float bias_full = (v + Wgs[b * 256 + o] * d1 +
                                 wgb[o] * (d2 + 4096.0f * d1)) * invN;
        const float sc = bn_gamma[o] * rsqrtf(bn_var[o] + BN_EPS);
        bias_out[b * 256 + o] = sc * (bias_full - bn_mean[o]) + bn_beta[o];
      }
    }
  }
}

// ================= out[b] = W_out[b] @ a[b] + bias (MFMA, 32-wide n-tiles) =======
__global__ __launch_bounds__(256) void out_mfma_kernel(const __bf16* __restrict__ Whi,
                                                       const __bf16* __restrict__ Wlo,
                                                       const __bf16* __restrict__ at,
                                                       const float* __restrict__ bias_out,
                                                       float* __restrict__ out) {
  const int nt = blockIdx.x, mt = blockIdx.y, b = blockIdx.z;
  const int wave = threadIdx.x >> 6, lane = threadIdx.x & 63;
  const int m = lane & 15, q = lane >> 4;
  const int o = mt * 64 + wave * 16 + m;
  const __bf16* wh = Whi + (size_t)b * 65536 + (size_t)o * 256;
  const __bf16* wl = Wlo + (size_t)b * 65536 + (size_t)o * 256;
  const __bf16* atb = at + ((size_t)b * NSP + nt * 32) * CCH;
  f32x4 acc[2] = {};
#pragma unroll
  for (int ks = 0; ks < 8; ++ks) {
    const int k = ks * 32 + q * 8;
    const bf16x8 ah = *(const bf16x8*)(wh + k);
    const bf16x8 al = *(const bf16x8*)(wl + k);
#pragma unroll
    for (int t4 = 0; t4 < 2; ++t4) {
      const bf16x8 bh = *(const bf16x8*)(atb + (size_t)(t4 * 16 + m) * 256 + k);
      acc[t4] = __builtin_amdgcn_mfma_f32_16x16x32_bf16(ah, bh, acc[t4], 0, 0, 0);
      acc[t4] = __builtin_amdgcn_mfma_f32_16x16x32_bf16(al, bh, acc[t4], 0, 0, 0);
    }
  }
  float* ob = out + (size_t)b * CCH * NSP;
#pragma unroll
  for (int r = 0; r < 4; ++r) {
    const int orow = mt * 64 + wave * 16 + q * 4 + r;
    const float bo = bias_out[b * 256 + orow];
#pragma unroll
    for (int t4 = 0; t4 < 2; ++t4)
      ob[(size_t)orow * NSP + nt * 32 + t4 * 16 + m] = acc[t4][r] + bo;
  }
}

extern "C" void kernel_launch(void* const* d_in, const int* in_sizes, int n_in,
                              void* d_out, int out_size, void* d_ws, size_t ws_size,
                              hipStream_t stream) {
  (void)in_sizes; (void)n_in; (void)out_size; (void)ws_size;
  const float* a       = (const float*)d_in[0];
  const float* bI      = (const float*)d_in[1];
  const float* theta_w = (const float*)d_in[2];
  const float* theta_b = (const float*)d_in[3];
  const float* phi_w   = (const float*)d_in[4];
  const float* phi_b   = (const float*)d_in[5];
  const float* g_w     = (const float*)d_in[6];
  const float* g_b     = (const float*)d_in[7];
  const float* W_w     = (const float*)d_in[8];
  const float* bn_gamma= (const float*)d_in[9];
  const float* bn_beta = (const float*)d_in[10];
  const float* bn_mean = (const float*)d_in[11];
  const float* bn_var  = (const float*)d_in[12];
  float* out = (float*)d_out;
  float* ws  = (float*)d_ws;

  // fp32 region (float offsets)
  float* Gpart    = ws;                  // 4194304 (16 MB)
  float* srow     = ws + 4194304;        // 1024
  float* Wg       = ws + 4195328;        // 65536
  float* bias_out = ws + 4260864;        // 1024
  float* Wgs      = ws + 4261888;        // 1024
  float* sPTv     = ws + 4262912;        // 1024
  float* wgb      = ws + 4263936;        // 256
  float* vpt      = ws + 4264192;        // 256
  float* vb_g     = ws + 4264448;        // 256
  float* t2_g     = ws + 4264704;        // 1024
  float* dvec     = ws + 4265728;        // 8
  // bf16 region
  __bf16* at    = (__bf16*)(ws + 4265984);   // 8 MB
  __bf16* Wghi  = (__bf16*)(ws + 6363136);   // 128 KB each below
  __bf16* Wglo  = (__bf16*)(ws + 6395904);
  __bf16* PTthi = (__bf16*)(ws + 6428672);
  __bf16* PTtlo = (__bf16*)(ws + 6461440);
  __bf16* W2hi  = (__bf16*)(ws + 6494208);   // 512 KB each below
  __bf16* W2lo  = (__bf16*)(ws + 6625280);
  __bf16* Whi   = (__bf16*)(ws + 6756352);
  __bf16* Wlo   = (__bf16*)(ws + 6887424);   // end ~28 MB

  front_kernel<<<dim3(3110), dim3(256), 0, stream>>>(bI, a, W_w, g_w, phi_w, theta_w,
                                                     phi_b, theta_b, g_b,
                                                     Gpart, srow, Wg, Wghi, Wglo,
                                                     PTthi, PTtlo, at,
                                                     vb_g, vpt, wgb, dvec);
  redw2_kernel<<<dim3(320), dim3(256), 0, stream>>>(Gpart, vb_g, t2_g, srow, Wg,
                                                    Wghi, Wglo, PTthi, PTtlo,
                                                    W2hi, W2lo, Wgs, sPTv, dvec);
  wout_mfma_kernel<<<dim3(272), dim3(256), 0, stream>>>(W2hi, W2lo, PTthi, PTtlo,
                                                        Wgs, sPTv, wgb, vpt, Wg, t2_g,
                                                        dvec, bn_gamma, bn_beta, bn_mean,
                                                        bn_var, Whi, Wlo, bias_out);
  out_mfma_kernel<<<dim3(128, 4, 4), dim3(256), 0, stream>>>(Whi, Wlo, at, bias_out, out);
}